// Round 2
// 408.019 us; speedup vs baseline: 1.0028x; 1.0028x over previous
//
#include <hip/hip_runtime.h>

// out[b][ctr][h][w] = sum_c a[b][c][h][w] * b[b][c][h][w - 40 + ctr], ctr 0..40.
// B=8, C=128, H=192, W=256.  Per (b,h) row: banded A^T*Bp via 16x16x32 bf16 MFMA.
//
// V3 = V2 with the reader-side barrier race fixed (m152 lesson):
//  - every barrier separating "readers of chunk k" from "writers of chunk k+1"
//    now drains the reader's own lgkmcnt before s_barrier (DS_BAR). V2's bare
//    s_barrier allowed a wave to arrive with fragment ds_reads still queued
//    while another wave passed and overwrote the tile -> stale/torn fragments.
//  - vmcnt is still never drained at barriers: global prefetch loads stay in
//    flight across the convert/LDS/MFMA phases (the latency-hiding lever).
//  - 512-thread blocks (8 waves sharing one 44.8KB tile), 1-deep register
//    prefetch, pad zeroed once, 5 shared b-fragments per wave-chunk.

constexpr int Bsz = 8, Cch = 128, Hh = 192, Ww = 256, NC = 41;
constexpr int CHW = Hh * Ww;          // 49152
constexpr int LDB = 40;               // u16 per spatial row (32 c + 8 pad) = 80 B
constexpr int A_BYTES = 256 * LDB * 2;   // 20480
constexpr int OSTRIDE = 260;          // f32 epilogue row stride (1040 B)
// smem = max(20480 + 304*80 = 44800, 41*260*4 = 42640) = 44800 B

using sh4 = __attribute__((ext_vector_type(4))) short;
using sh8 = __attribute__((ext_vector_type(8))) short;
using fx4 = __attribute__((ext_vector_type(4))) float;

__device__ inline unsigned short f2bf(float x) {   // fp32 -> bf16 RNE
    unsigned int u = __float_as_uint(x);
    u += 0x7fffu + ((u >> 16) & 1u);
    return (unsigned short)(u >> 16);
}

__global__ __launch_bounds__(512, 4)
void corr_mfma(const float* __restrict__ A, const float* __restrict__ B,
               float* __restrict__ O) {
    __shared__ __align__(16) unsigned char smem[44800];
    unsigned short* aT   = (unsigned short*)smem;              // [256 w][40 c] bf16
    unsigned short* bT   = (unsigned short*)(smem + A_BYTES);  // [304 u][40 c] bf16
    float*          outp = (float*)smem;                       // [41][260] f32 (epilogue)

    const int tid  = threadIdx.x;
    const int lane = tid & 63, wave = tid >> 6;
    const int row  = blockIdx.x;
    const int bb   = row / Hh, h = row - bb * Hh;

    const float* base_a = A + (size_t)bb * Cch * CHW + (size_t)h * Ww;
    const float* base_b = B + (size_t)bb * Cch * CHW + (size_t)h * Ww;

    // staging cell: thread loads 4 channels x float4 per tensor per chunk
    const int cg = tid & 7;     // channel subgroup (4 channels each)
    const int w4 = tid >> 3;    // float4 column group 0..63
    const int wi = lane & 15, kg = lane >> 4;

    const float* pa0 = base_a + (size_t)(cg * 4) * CHW + w4 * 4;
    const float* pb0 = base_b + (size_t)(cg * 4) * CHW + w4 * 4;

    fx4 acc[2][4];
#pragma unroll
    for (int i = 0; i < 2; ++i)
#pragma unroll
        for (int j = 0; j < 4; ++j) acc[i][j] = (fx4)0.0f;

    float4 rA[2][4], rB[2][4];   // double-buffered prefetch registers

#define ISSUE(S, K)                                                           \
    _Pragma("unroll")                                                         \
    for (int i = 0; i < 4; ++i)                                               \
        rA[S][i] = *(const float4*)(pa0 + (size_t)((K) * 32 + i) * CHW);      \
    _Pragma("unroll")                                                         \
    for (int i = 0; i < 4; ++i)                                               \
        rB[S][i] = *(const float4*)(pb0 + (size_t)((K) * 32 + i) * CHW);

#define CONV_STORE(S)                                                         \
    {                                                                         \
        const float* fa = (const float*)&rA[S][0];                            \
        const float* fb = (const float*)&rB[S][0];                            \
        _Pragma("unroll")                                                     \
        for (int r = 0; r < 4; ++r) {                                         \
            sh4 s;                                                            \
            _Pragma("unroll")                                                 \
            for (int i = 0; i < 4; ++i) s[i] = (short)f2bf(fa[i * 4 + r]);    \
            *(sh4*)(aT + (w4 * 4 + r) * LDB + cg * 4) = s;                    \
        }                                                                     \
        _Pragma("unroll")                                                     \
        for (int r = 0; r < 4; ++r) {                                         \
            sh4 s;                                                            \
            _Pragma("unroll")                                                 \
            for (int i = 0; i < 4; ++i) s[i] = (short)f2bf(fb[i * 4 + r]);    \
            *(sh4*)(bT + (40 + w4 * 4 + r) * LDB + cg * 4) = s;               \
        }                                                                     \
    }

    // wave owns 32 w's: w = wave*32 + i*16 + wi, i in {0,1}; u-tiles i+j overlap
#define MFMA_STEP()                                                           \
    {                                                                         \
        const int w0 = wave * 32;                                             \
        sh8 afr[2], bfr[5];                                                   \
        _Pragma("unroll")                                                     \
        for (int i = 0; i < 2; ++i)                                           \
            afr[i] = *(const sh8*)(aT + (w0 + i * 16 + wi) * LDB + kg * 8);   \
        _Pragma("unroll")                                                     \
        for (int t = 0; t < 5; ++t)                                           \
            bfr[t] = *(const sh8*)(bT + (w0 + t * 16 + wi) * LDB + kg * 8);   \
        _Pragma("unroll")                                                     \
        for (int i = 0; i < 2; ++i)                                           \
            _Pragma("unroll")                                                 \
            for (int j = 0; j < 4; ++j)                                       \
                acc[i][j] = __builtin_amdgcn_mfma_f32_16x16x32_bf16(          \
                    bfr[i + j], afr[i], acc[i][j], 0, 0, 0);                  \
    }

    // DS-safe barrier: drain this wave's own LDS reads AND writes (lgkmcnt)
    // before signaling; vmcnt deliberately untouched so global prefetch loads
    // stay in flight across the barrier.
#define DS_BAR()                                           \
    asm volatile("s_waitcnt lgkmcnt(0)" ::: "memory");     \
    __builtin_amdgcn_s_barrier();                          \
    asm volatile("" ::: "memory");

    ISSUE(0, 0)
    // zero left pad ONCE: rows u=0..39 are never rewritten by staging
    if (tid < 320) {
        int u = tid >> 3, cz = (tid & 7) * 4;
        *(sh4*)(bT + u * LDB + cz) = (sh4)0;
    }
    ISSUE(1, 1)          // chunk1 in flight while chunk0 converts
    CONV_STORE(0)
    ISSUE(0, 2)          // chunk2 in flight across chunk0's MFMA phase
    DS_BAR()             // staging of chunk0 visible to all waves
    MFMA_STEP()          // chunk 0
    DS_BAR()             // all waves' fragment reads of chunk0 DRAINED
    CONV_STORE(1)
    ISSUE(1, 3)          // chunk3 in flight across chunk1's MFMA phase
    DS_BAR()
    MFMA_STEP()          // chunk 1
    DS_BAR()
    CONV_STORE(0)
    DS_BAR()
    MFMA_STEP()          // chunk 2
    DS_BAR()
    CONV_STORE(1)
    DS_BAR()
    MFMA_STEP()          // chunk 3

    DS_BAR()             // all fragment reads drained; smem reused as outp
    // scatter valid band entries: D row = ui = kg*4 + r, col = wi; ctr = 16j + ui - wi
#pragma unroll
    for (int i = 0; i < 2; ++i) {
        const int w0 = wave * 32 + i * 16;
#pragma unroll
        for (int j = 0; j < 4; ++j)
#pragma unroll
            for (int r = 0; r < 4; ++r) {
                int ctr = 16 * j + (kg * 4 + r) - wi;
                if ((unsigned)ctr <= 40u) outp[ctr * OSTRIDE + w0 + wi] = acc[i][j][r];
            }
    }
    DS_BAR()
    // coalesced float4 store of the [41][256] plane
    float* obase = O + ((size_t)bb * NC * Hh + (size_t)h) * Ww;
    for (int idx = tid; idx < NC * 64; idx += 512) {
        int ctr = idx >> 6, q = idx & 63;
        float4 v = *(const float4*)(outp + ctr * OSTRIDE + q * 4);
        *(float4*)(obase + (size_t)ctr * CHW + q * 4) = v;
    }
}

extern "C" void kernel_launch(void* const* d_in, const int* in_sizes, int n_in,
                              void* d_out, int out_size, void* d_ws, size_t ws_size,
                              hipStream_t stream) {
    const float* a = (const float*)d_in[0];
    const float* b = (const float*)d_in[1];
    // d_in[2] = max_displacement (40) — hardcoded.
    float* out = (float*)d_out;
    corr_mfma<<<dim3(Bsz * Hh), dim3(512), 0, stream>>>(a, b, out);
}